// Round 5
// baseline (189.869 us; speedup 1.0000x reference)
//
#include <hip/hip_runtime.h>
#include <math.h>

#define H 256
#define L 50
#define V 50257
#define LOGIT_BLKS 786   // 786 blk * 4 waves * 16 rows = 50304 >= V
#define H2_BLKS 64
#define TOTAL4 (V * H / 4)   // out_W in float4 units = 3,216,448

__device__ __forceinline__ float dot4(float4 a, float4 b) {
    return a.x * b.x + a.y * b.y + a.z * b.z + a.w * b.w;
}

__device__ __forceinline__ float wave_reduce_sum(float v) {
#pragma unroll
    for (int m = 32; m >= 1; m >>= 1) v += __shfl_xor(v, m, 64);
    return v;
}

__device__ __forceinline__ float wave_reduce_max(float v) {
#pragma unroll
    for (int m = 32; m >= 1; m >>= 1) v = fmaxf(v, __shfl_xor(v, m, 64));
    return v;
}

__device__ __forceinline__ float sigmoidf(float x) { return 1.0f / (1.0f + __expf(-x)); }

__device__ __forceinline__ void ms_push(float& m, float& s, float x) {
    float mn = fmaxf(m, x);
    s = s * __expf(m - mn) + __expf(x - mn);
    m = mn;
}
__device__ __forceinline__ void ms_merge(float& m, float& s, float om, float os) {
    float M = fmaxf(m, om);
    float a = (m == -INFINITY) ? 0.f : s * __expf(m - M);
    float c = (om == -INFINITY) ? 0.f : os * __expf(om - M);
    m = M; s = a + c;
}

// Stream a slice [beg4, fin4) of out_W (float4 units) through the caches.
// Sum into a sink store so it can't be DCE'd. L3 is wiped every iteration by
// the harness's 256MiB ws poison-fill, so this re-warms it (R3: FETCH showed
// the later logits read hit cache after an in-kernel prefetch).
__device__ __forceinline__ void prefetch_slice(
    const float4* __restrict__ w4, int beg4, int fin4, float* __restrict__ sink,
    int slot)
{
    int t = threadIdx.x, lane = t & 63;
    float acc = 0.f;
    for (int i = beg4 + t; i < fin4; i += 256) {
        float4 q = w4[i];
        acc += q.x + q.y + q.z + q.w;
    }
    acc = wave_reduce_sum(acc);
    if (lane == 0) sink[slot] = acc;
}

// One GRU output element j computed by one wave.
__device__ __forceinline__ void gru_wave(
    int j, int lane, float4 xv, float4 hv, float hj,
    const float* __restrict__ w_ih, const float* __restrict__ w_hh,
    const float* __restrict__ b_ih, const float* __restrict__ b_hh,
    float* __restrict__ outp)
{
    float gi[3], gh[3];
#pragma unroll
    for (int k = 0; k < 3; ++k) {
        int row = k * H + j;
        const float4* wi4 = (const float4*)(w_ih + (size_t)row * H);
        const float4* wh4 = (const float4*)(w_hh + (size_t)row * H);
        gi[k] = wave_reduce_sum(dot4(wi4[lane], xv)) + b_ih[row];
        gh[k] = wave_reduce_sum(dot4(wh4[lane], hv)) + b_hh[row];
    }
    if (lane == 0) {
        float r = sigmoidf(gi[0] + gh[0]);
        float z = sigmoidf(gi[1] + gh[1]);
        float n = tanhf(gi[2] + r * gh[2]);
        outp[j] = (1.f - z) * n + z * hj;
    }
}

// ---- K1: scores (redundant per block) + softmax + applied + comb row.
// Blocks 0..63 work; 64..511 prefetch out_W[0 .. PF1).
#define PF1 1000000
__global__ __launch_bounds__(256) void k_comb(
    const int* __restrict__ token, const float* __restrict__ hidden,
    const float* __restrict__ emb, const float* __restrict__ enc,
    const float* __restrict__ attn_W, const float* __restrict__ attn_b,
    const float* __restrict__ comb_W, const float* __restrict__ comb_b,
    const float* __restrict__ out_W,
    float* __restrict__ ws_x, float* __restrict__ out_aw, float* __restrict__ sink)
{
    int b = blockIdx.x, t = threadIdx.x, wid = t >> 6, lane = t & 63;
    if (b >= 64) {
        int i = b - 64;                         // 448 prefetch blocks
        const int per = (PF1 + 447) / 448;
        prefetch_slice((const float4*)out_W, i * per, min(PF1, (i + 1) * per),
                       sink, b * 4 + wid);
        return;
    }
    __shared__ __align__(16) float s_eh[2 * H];   // [e|h0] -> [e|applied]
    __shared__ float s_scores[L];
    __shared__ float s_aw[64];
    int tok = token[0];
    s_eh[t] = emb[(size_t)tok * H + t];
    s_eh[H + t] = hidden[t];
    __syncthreads();
    for (int l = wid; l < L; l += 4) {            // all 50 scores, this block
        float acc = 0.f;
#pragma unroll
        for (int c = 0; c < 8; ++c)
            acc += attn_W[l * 2 * H + c * 64 + lane] * s_eh[c * 64 + lane];
        acc = wave_reduce_sum(acc);
        if (lane == 0) s_scores[l] = fmaxf(acc + attn_b[l], 0.f);  // relu
    }
    __syncthreads();
    if (t < 64) {                                  // softmax over 50, wave 0
        float v = (t < L) ? s_scores[t] : -INFINITY;
        float mx = wave_reduce_max(v);
        float e = (t < L) ? __expf(v - mx) : 0.f;
        float ssum = wave_reduce_sum(e);
        if (t < L) {
            float aw = e / ssum;
            s_aw[t] = aw;
            if (b == 0) out_aw[t] = aw;            // third output
        }
    }
    __syncthreads();
    float app = 0.f;
    for (int l = 0; l < L; ++l) app += s_aw[l] * enc[l * H + t];
    s_eh[H + t] = app;                             // cat = [e|applied]
    __syncthreads();
    int row = b * 4 + wid;
    const float4* c4 = (const float4*)s_eh;
    const float4* W4 = (const float4*)(comb_W + (size_t)row * 2 * H);
    float acc = dot4(W4[lane], c4[lane]) + dot4(W4[lane + 64], c4[lane + 64]);
    acc = wave_reduce_sum(acc);
    if (lane == 0) ws_x[row] = fmaxf(acc + comb_b[row], 0.f);
}

// ---- K2: bidirectional GRU (blocks 0..127); 128..511 prefetch [PF1, PF1+PF2)
#define PF2 1000000
__global__ __launch_bounds__(256) void k_gru_fb(
    const float* __restrict__ ws_x, const float* __restrict__ hidden,
    const float* __restrict__ w_ih_f, const float* __restrict__ w_hh_f,
    const float* __restrict__ b_ih_f, const float* __restrict__ b_hh_f,
    const float* __restrict__ w_ih_b, const float* __restrict__ w_hh_b,
    const float* __restrict__ b_ih_b, const float* __restrict__ b_hh_b,
    const float* __restrict__ out_W,
    float* __restrict__ ws_hf, float* __restrict__ ws_hb, float* __restrict__ sink)
{
    int b = blockIdx.x, t = threadIdx.x, wid = t >> 6, lane = t & 63;
    if (b >= 128) {
        int i = b - 128;                        // 384 prefetch blocks
        const int per = (PF2 + 383) / 384;
        prefetch_slice((const float4*)out_W, PF1 + i * per,
                       PF1 + min(PF2, (i + 1) * per), sink, b * 4 + wid);
        return;
    }
    int g = b * 4 + wid;
    int dir = g >> 8, j = g & 255;
    gru_wave(j, lane, ((const float4*)ws_x)[lane], ((const float4*)hidden)[lane],
             hidden[j],
             dir ? w_ih_b : w_ih_f, dir ? w_hh_b : w_hh_f,
             dir ? b_ih_b : b_ih_f, dir ? b_hh_b : b_hh_f,
             dir ? ws_hb : ws_hf);
}

// ---- K3: h1 = gru(hf, mean(hf,hb)) (blocks 0..63); 64..511 prefetch PF3 ----
#define PF3 500000
__global__ __launch_bounds__(256) void k_gru1(
    const float* __restrict__ ws_hf, const float* __restrict__ ws_hb,
    const float* __restrict__ w_ih_g, const float* __restrict__ w_hh_g,
    const float* __restrict__ b_ih_g, const float* __restrict__ b_hh_g,
    const float* __restrict__ out_W,
    float* __restrict__ ws_h1, float* __restrict__ sink)
{
    int b = blockIdx.x, t = threadIdx.x, wid = t >> 6, lane = t & 63;
    if (b >= 64) {
        int i = b - 64;                         // 448 prefetch blocks
        const int per = (PF3 + 447) / 448;
        prefetch_slice((const float4*)out_W, PF1 + PF2 + i * per,
                       PF1 + PF2 + min(PF3, (i + 1) * per), sink, b * 4 + wid);
        return;
    }
    int j = b * 4 + wid;
    float4 av = ((const float4*)ws_hf)[lane];
    float4 bv = ((const float4*)ws_hb)[lane];
    float4 hv = make_float4(0.5f * (av.x + bv.x), 0.5f * (av.y + bv.y),
                            0.5f * (av.z + bv.z), 0.5f * (av.w + bv.w));
    float hj = 0.5f * (ws_hf[j] + ws_hb[j]);
    gru_wave(j, lane, av, hv, hj, w_ih_g, w_hh_g, b_ih_g, b_hh_g, ws_h1);
}

// ---- K4: logits + per-block (m,s) partials (0..785) || h2 (786..849) -------
__global__ __launch_bounds__(256) void k_logits(
    const float* __restrict__ out_W, const float* __restrict__ out_b,
    const float* __restrict__ h1, const float* __restrict__ ws_hb,
    const float* __restrict__ w_ih_g, const float* __restrict__ w_hh_g,
    const float* __restrict__ b_ih_g, const float* __restrict__ b_hh_g,
    float* __restrict__ logits, float* __restrict__ out_h2,
    float* __restrict__ part_m, float* __restrict__ part_s)
{
    int b = blockIdx.x, t = threadIdx.x, wid = t >> 6, lane = t & 63;
    if (b >= LOGIT_BLKS) {
        int j = (b - LOGIT_BLKS) * 4 + wid;    // h2 = gru(hb, h1)
        gru_wave(j, lane, ((const float4*)ws_hb)[lane], ((const float4*)h1)[lane],
                 h1[j], w_ih_g, w_hh_g, b_ih_g, b_hh_g, out_h2);
        return;
    }
    __shared__ float s_m4[4], s_s4[4];
    float4 hv = ((const float4*)h1)[lane];
    int base = (b * 4 + wid) * 16;
    float m = -INFINITY, s = 0.f;
#pragma unroll 1
    for (int k = 0; k < 16; k += 2) {
        int v = base + k;
        if (v >= V) break;
        const float4* W0 = (const float4*)(out_W + (size_t)v * H);
        float4 a0 = W0[lane];
        bool has2 = (v + 1 < V);
        float4 a1 = has2 ? ((const float4*)(out_W + (size_t)(v + 1) * H))[lane]
                         : make_float4(0.f, 0.f, 0.f, 0.f);
        float x0 = wave_reduce_sum(dot4(a0, hv)) + out_b[v];
        float x1 = wave_reduce_sum(dot4(a1, hv));
        if (lane == 0) logits[v] = x0;
        ms_push(m, s, x0);
        if (has2) {
            x1 += out_b[v + 1];
            if (lane == 0) logits[v + 1] = x1;
            ms_push(m, s, x1);
        }
    }
    if (lane == 0) { s_m4[wid] = m; s_s4[wid] = s; }
    __syncthreads();
    if (t == 0) {
        float M = s_m4[0], S = s_s4[0];
#pragma unroll
        for (int q = 1; q < 4; ++q) ms_merge(M, S, s_m4[q], s_s4[q]);
        part_m[b] = M; part_s[b] = S;
    }
}

// ---- K5: fold 786 partials -> lse (replicated); subtract -------------------
__global__ __launch_bounds__(256) void k_final(
    const float* __restrict__ part_m, const float* __restrict__ part_s,
    float* __restrict__ logits)
{
    __shared__ float s_m4[4], s_s4[4];
    __shared__ float s_bcast;
    int t = threadIdx.x, wid = t >> 6, lane = t & 63;
    float m = -INFINITY, s = 0.f;
    for (int idx = t; idx < LOGIT_BLKS; idx += 256)
        ms_merge(m, s, part_m[idx], part_s[idx]);
#pragma unroll
    for (int d = 32; d >= 1; d >>= 1) {
        float om = __shfl_xor(m, d, 64);
        float os = __shfl_xor(s, d, 64);
        ms_merge(m, s, om, os);
    }
    if (lane == 0) { s_m4[wid] = m; s_s4[wid] = s; }
    __syncthreads();
    if (t == 0) {
        float M = s_m4[0], S = s_s4[0];
#pragma unroll
        for (int q = 1; q < 4; ++q) ms_merge(M, S, s_m4[q], s_s4[q]);
        s_bcast = M + logf(S);
    }
    __syncthreads();
    float lse = s_bcast;
    int i = blockIdx.x * 256 + t;
    if (i < V) logits[i] -= lse;
}

extern "C" void kernel_launch(void* const* d_in, const int* in_sizes, int n_in,
                              void* d_out, int out_size, void* d_ws, size_t ws_size,
                              hipStream_t stream)
{
    const int*   token  = (const int*)d_in[0];
    const float* hidden = (const float*)d_in[1];
    const float* enc    = (const float*)d_in[2];
    const float* emb    = (const float*)d_in[3];
    const float* attn_W = (const float*)d_in[4];
    const float* attn_b = (const float*)d_in[5];
    const float* comb_W = (const float*)d_in[6];
    const float* comb_b = (const float*)d_in[7];
    const float* w_ih_f = (const float*)d_in[8];
    const float* w_hh_f = (const float*)d_in[9];
    const float* b_ih_f = (const float*)d_in[10];
    const float* b_hh_f = (const float*)d_in[11];
    const float* w_ih_b = (const float*)d_in[12];
    const float* w_hh_b = (const float*)d_in[13];
    const float* b_ih_b = (const float*)d_in[14];
    const float* b_hh_b = (const float*)d_in[15];
    const float* w_ih_g = (const float*)d_in[16];
    const float* w_hh_g = (const float*)d_in[17];
    const float* b_ih_g = (const float*)d_in[18];
    const float* b_hh_g = (const float*)d_in[19];
    const float* out_W  = (const float*)d_in[20];
    const float* out_b  = (const float*)d_in[21];

    float* out = (float*)d_out;   // [V logp | H h2 | L aw]
    float* ws  = (float*)d_ws;
    float* ws_x   = ws;               // 256
    float* ws_hf  = ws + 256;         // 256
    float* ws_hb  = ws + 512;         // 256
    float* ws_h1  = ws + 768;         // 256
    float* part_m = ws + 1088;        // 786
    float* part_s = ws + 1888;        // 786
    float* sink   = ws + 4096;        // 2048 (prefetch DCE sink)

    k_comb<<<512, 256, 0, stream>>>(token, hidden, emb, enc, attn_W, attn_b,
                                    comb_W, comb_b, out_W, ws_x, out + V + H, sink);
    k_gru_fb<<<512, 256, 0, stream>>>(ws_x, hidden,
                                      w_ih_f, w_hh_f, b_ih_f, b_hh_f,
                                      w_ih_b, w_hh_b, b_ih_b, b_hh_b,
                                      out_W, ws_hf, ws_hb, sink);
    k_gru1<<<512, 256, 0, stream>>>(ws_hf, ws_hb,
                                    w_ih_g, w_hh_g, b_ih_g, b_hh_g,
                                    out_W, ws_h1, sink);
    k_logits<<<LOGIT_BLKS + H2_BLKS, 256, 0, stream>>>(
        out_W, out_b, ws_h1, ws_hb, w_ih_g, w_hh_g, b_ih_g, b_hh_g,
        out, out + V, part_m, part_s);
    k_final<<<197, 256, 0, stream>>>(part_m, part_s, out);
}

// Round 6
// 185.400 us; speedup vs baseline: 1.0241x; 1.0241x over previous
//
#include <hip/hip_runtime.h>
#include <math.h>

#define H 256
#define L 50
#define V 50257
#define LOGIT_BLKS 786   // 786 blk * 4 waves * 16 rows = 50304 >= V
#define H2_BLKS 64

__device__ __forceinline__ float dot4(float4 a, float4 b) {
    return a.x * b.x + a.y * b.y + a.z * b.z + a.w * b.w;
}

__device__ __forceinline__ float wave_reduce_sum(float v) {
#pragma unroll
    for (int m = 32; m >= 1; m >>= 1) v += __shfl_xor(v, m, 64);
    return v;
}

__device__ __forceinline__ float wave_reduce_max(float v) {
#pragma unroll
    for (int m = 32; m >= 1; m >>= 1) v = fmaxf(v, __shfl_xor(v, m, 64));
    return v;
}

__device__ __forceinline__ float sigmoidf(float x) { return 1.0f / (1.0f + __expf(-x)); }

__device__ __forceinline__ void ms_push(float& m, float& s, float x) {
    float mn = fmaxf(m, x);
    s = s * __expf(m - mn) + __expf(x - mn);
    m = mn;
}
__device__ __forceinline__ void ms_merge(float& m, float& s, float om, float os) {
    float M = fmaxf(m, om);
    float a = (m == -INFINITY) ? 0.f : s * __expf(m - M);
    float c = (om == -INFINITY) ? 0.f : os * __expf(om - M);
    m = M; s = a + c;
}

// One GRU output element j computed by one wave.
__device__ __forceinline__ void gru_wave(
    int j, int lane, float4 xv, float4 hv, float hj,
    const float* __restrict__ w_ih, const float* __restrict__ w_hh,
    const float* __restrict__ b_ih, const float* __restrict__ b_hh,
    float* __restrict__ outp)
{
    float gi[3], gh[3];
#pragma unroll
    for (int k = 0; k < 3; ++k) {
        int row = k * H + j;
        const float4* wi4 = (const float4*)(w_ih + (size_t)row * H);
        const float4* wh4 = (const float4*)(w_hh + (size_t)row * H);
        gi[k] = wave_reduce_sum(dot4(wi4[lane], xv)) + b_ih[row];
        gh[k] = wave_reduce_sum(dot4(wh4[lane], hv)) + b_hh[row];
    }
    if (lane == 0) {
        float r = sigmoidf(gi[0] + gh[0]);
        float z = sigmoidf(gi[1] + gh[1]);
        float n = tanhf(gi[2] + r * gh[2]);
        outp[j] = (1.f - z) * n + z * hj;
    }
}

// ---- K1 (64 blocks): scores (redundant per block, L2-hot) + softmax +
// applied + one comb row per wave. No prefetch (R5: prefetch was a net loss).
__global__ __launch_bounds__(256) void k_comb(
    const int* __restrict__ token, const float* __restrict__ hidden,
    const float* __restrict__ emb, const float* __restrict__ enc,
    const float* __restrict__ attn_W, const float* __restrict__ attn_b,
    const float* __restrict__ comb_W, const float* __restrict__ comb_b,
    float* __restrict__ ws_x, float* __restrict__ out_aw)
{
    __shared__ __align__(16) float s_eh[2 * H];   // [e|h0] -> [e|applied]
    __shared__ float s_scores[L];
    __shared__ float s_aw[64];
    int b = blockIdx.x, t = threadIdx.x, wid = t >> 6, lane = t & 63;
    int tok = token[0];
    s_eh[t] = emb[(size_t)tok * H + t];
    s_eh[H + t] = hidden[t];
    __syncthreads();
    for (int l = wid; l < L; l += 4) {            // all 50 scores, this block
        float acc = 0.f;
#pragma unroll
        for (int c = 0; c < 8; ++c)
            acc += attn_W[l * 2 * H + c * 64 + lane] * s_eh[c * 64 + lane];
        acc = wave_reduce_sum(acc);
        if (lane == 0) s_scores[l] = fmaxf(acc + attn_b[l], 0.f);  // relu
    }
    __syncthreads();
    if (t < 64) {                                  // softmax over 50, wave 0
        float v = (t < L) ? s_scores[t] : -INFINITY;
        float mx = wave_reduce_max(v);
        float e = (t < L) ? __expf(v - mx) : 0.f;
        float ssum = wave_reduce_sum(e);
        if (t < L) {
            float aw = e / ssum;
            s_aw[t] = aw;
            if (b == 0) out_aw[t] = aw;            // third output
        }
    }
    __syncthreads();
    float app = 0.f;
    for (int l = 0; l < L; ++l) app += s_aw[l] * enc[l * H + t];
    s_eh[H + t] = app;                             // cat = [e|applied]
    __syncthreads();
    int row = b * 4 + wid;
    const float4* c4 = (const float4*)s_eh;
    const float4* W4 = (const float4*)(comb_W + (size_t)row * 2 * H);
    float acc = dot4(W4[lane], c4[lane]) + dot4(W4[lane + 64], c4[lane + 64]);
    acc = wave_reduce_sum(acc);
    if (lane == 0) ws_x[row] = fmaxf(acc + comb_b[row], 0.f);
}

// ---- K2 (128 blocks): bidirectional GRU (hf, hb), wave per (dir, j) --------
__global__ __launch_bounds__(256) void k_gru_fb(
    const float* __restrict__ ws_x, const float* __restrict__ hidden,
    const float* __restrict__ w_ih_f, const float* __restrict__ w_hh_f,
    const float* __restrict__ b_ih_f, const float* __restrict__ b_hh_f,
    const float* __restrict__ w_ih_b, const float* __restrict__ w_hh_b,
    const float* __restrict__ b_ih_b, const float* __restrict__ b_hh_b,
    float* __restrict__ ws_hf, float* __restrict__ ws_hb)
{
    int t = threadIdx.x, wid = t >> 6, lane = t & 63;
    int g = blockIdx.x * 4 + wid;
    int dir = g >> 8, j = g & 255;
    gru_wave(j, lane, ((const float4*)ws_x)[lane], ((const float4*)hidden)[lane],
             hidden[j],
             dir ? w_ih_b : w_ih_f, dir ? w_hh_b : w_hh_f,
             dir ? b_ih_b : b_ih_f, dir ? b_hh_b : b_hh_f,
             dir ? ws_hb : ws_hf);
}

// ---- K3 (64 blocks): h1 = gru(hf, mean(hf,hb)) -----------------------------
__global__ __launch_bounds__(256) void k_gru1(
    const float* __restrict__ ws_hf, const float* __restrict__ ws_hb,
    const float* __restrict__ w_ih_g, const float* __restrict__ w_hh_g,
    const float* __restrict__ b_ih_g, const float* __restrict__ b_hh_g,
    float* __restrict__ ws_h1)
{
    int t = threadIdx.x, wid = t >> 6, lane = t & 63;
    int j = blockIdx.x * 4 + wid;
    float4 av = ((const float4*)ws_hf)[lane];
    float4 bv = ((const float4*)ws_hb)[lane];
    float4 hv = make_float4(0.5f * (av.x + bv.x), 0.5f * (av.y + bv.y),
                            0.5f * (av.z + bv.z), 0.5f * (av.w + bv.w));
    float hj = 0.5f * (ws_hf[j] + ws_hb[j]);
    gru_wave(j, lane, av, hv, hj, w_ih_g, w_hh_g, b_ih_g, b_hh_g, ws_h1);
}

// ---- K4: logits + per-block (m,s) partials (0..785) || h2 (786..849) -------
// 16 rows per wave, 4 rows in flight (4 x 16B/lane outstanding -> HBM sat).
__global__ __launch_bounds__(256) void k_logits(
    const float* __restrict__ out_W, const float* __restrict__ out_b,
    const float* __restrict__ h1, const float* __restrict__ ws_hb,
    const float* __restrict__ w_ih_g, const float* __restrict__ w_hh_g,
    const float* __restrict__ b_ih_g, const float* __restrict__ b_hh_g,
    float* __restrict__ logits, float* __restrict__ out_h2,
    float* __restrict__ part_m, float* __restrict__ part_s)
{
    int b = blockIdx.x, t = threadIdx.x, wid = t >> 6, lane = t & 63;
    if (b >= LOGIT_BLKS) {
        int j = (b - LOGIT_BLKS) * 4 + wid;    // h2 = gru(hb, h1)
        gru_wave(j, lane, ((const float4*)ws_hb)[lane], ((const float4*)h1)[lane],
                 h1[j], w_ih_g, w_hh_g, b_ih_g, b_hh_g, out_h2);
        return;
    }
    __shared__ float s_m4[4], s_s4[4];
    float4 hv = ((const float4*)h1)[lane];
    int base = (b * 4 + wid) * 16;
    float m = -INFINITY, s = 0.f;
#pragma unroll 1
    for (int k = 0; k < 16; k += 4) {
        int v = base + k;
        if (v >= V) break;
        const float4 zero = make_float4(0.f, 0.f, 0.f, 0.f);
        float4 a0 = ((const float4*)(out_W + (size_t)v * H))[lane];
        float4 a1 = (v + 1 < V) ? ((const float4*)(out_W + (size_t)(v + 1) * H))[lane] : zero;
        float4 a2 = (v + 2 < V) ? ((const float4*)(out_W + (size_t)(v + 2) * H))[lane] : zero;
        float4 a3 = (v + 3 < V) ? ((const float4*)(out_W + (size_t)(v + 3) * H))[lane] : zero;
        float x0 = wave_reduce_sum(dot4(a0, hv));
        float x1 = wave_reduce_sum(dot4(a1, hv));
        float x2 = wave_reduce_sum(dot4(a2, hv));
        float x3 = wave_reduce_sum(dot4(a3, hv));
        float xs[4] = {x0, x1, x2, x3};
#pragma unroll
        for (int i = 0; i < 4; ++i) {
            if (v + i < V) {
                float x = xs[i] + out_b[v + i];
                if (lane == 0) logits[v + i] = x;
                ms_push(m, s, x);
            }
        }
    }
    if (lane == 0) { s_m4[wid] = m; s_s4[wid] = s; }
    __syncthreads();
    if (t == 0) {
        float M = s_m4[0], S = s_s4[0];
#pragma unroll
        for (int q = 1; q < 4; ++q) ms_merge(M, S, s_m4[q], s_s4[q]);
        part_m[b] = M; part_s[b] = S;
    }
}

// ---- K5 (197 blocks): fold 786 partials -> lse (replicated); subtract ------
__global__ __launch_bounds__(256) void k_final(
    const float* __restrict__ part_m, const float* __restrict__ part_s,
    float* __restrict__ logits)
{
    __shared__ float s_m4[4], s_s4[4];
    __shared__ float s_bcast;
    int t = threadIdx.x, wid = t >> 6, lane = t & 63;
    float m = -INFINITY, s = 0.f;
    for (int idx = t; idx < LOGIT_BLKS; idx += 256)
        ms_merge(m, s, part_m[idx], part_s[idx]);
#pragma unroll
    for (int d = 32; d >= 1; d >>= 1) {
        float om = __shfl_xor(m, d, 64);
        float os = __shfl_xor(s, d, 64);
        ms_merge(m, s, om, os);
    }
    if (lane == 0) { s_m4[wid] = m; s_s4[wid] = s; }
    __syncthreads();
    if (t == 0) {
        float M = s_m4[0], S = s_s4[0];
#pragma unroll
        for (int q = 1; q < 4; ++q) ms_merge(M, S, s_m4[q], s_s4[q]);
        s_bcast = M + logf(S);
    }
    __syncthreads();
    float lse = s_bcast;
    int i = blockIdx.x * 256 + t;
    if (i < V) logits[i] -= lse;
}

extern "C" void kernel_launch(void* const* d_in, const int* in_sizes, int n_in,
                              void* d_out, int out_size, void* d_ws, size_t ws_size,
                              hipStream_t stream)
{
    const int*   token  = (const int*)d_in[0];
    const float* hidden = (const float*)d_in[1];
    const float* enc    = (const float*)d_in[2];
    const float* emb    = (const float*)d_in[3];
    const float* attn_W = (const float*)d_in[4];
    const float* attn_b = (const float*)d_in[5];
    const float* comb_W = (const float*)d_in[6];
    const float* comb_b = (const float*)d_in[7];
    const float* w_ih_f = (const float*)d_in[8];
    const float* w_hh_f = (const float*)d_in[9];
    const float* b_ih_f = (const float*)d_in[10];
    const float* b_hh_f = (const float*)d_in[11];
    const float* w_ih_b = (const float*)d_in[12];
    const float* w_hh_b = (const float*)d_in[13];
    const float* b_ih_b = (const float*)d_in[14];
    const float* b_hh_b = (const float*)d_in[15];
    const float* w_ih_g = (const float*)d_in[16];
    const float* w_hh_g = (const float*)d_in[17];
    const float* b_ih_g = (const float*)d_in[18];
    const float* b_hh_g = (const float*)d_in[19];
    const float* out_W  = (const float*)d_in[20];
    const float* out_b  = (const float*)d_in[21];

    float* out = (float*)d_out;   // [V logp | H h2 | L aw]
    float* ws  = (float*)d_ws;
    float* ws_x   = ws;               // 256
    float* ws_hf  = ws + 256;         // 256
    float* ws_hb  = ws + 512;         // 256
    float* ws_h1  = ws + 768;         // 256
    float* part_m = ws + 1088;        // 786
    float* part_s = ws + 1888;        // 786

    k_comb<<<64, 256, 0, stream>>>(token, hidden, emb, enc, attn_W, attn_b,
                                   comb_W, comb_b, ws_x, out + V + H);
    k_gru_fb<<<128, 256, 0, stream>>>(ws_x, hidden,
                                      w_ih_f, w_hh_f, b_ih_f, b_hh_f,
                                      w_ih_b, w_hh_b, b_ih_b, b_hh_b,
                                      ws_hf, ws_hb);
    k_gru1<<<64, 256, 0, stream>>>(ws_hf, ws_hb,
                                   w_ih_g, w_hh_g, b_ih_g, b_hh_g, ws_h1);
    k_logits<<<LOGIT_BLKS + H2_BLKS, 256, 0, stream>>>(
        out_W, out_b, ws_h1, ws_hb, w_ih_g, w_hh_g, b_ih_g, b_hh_g,
        out, out + V, part_m, part_s);
    k_final<<<197, 256, 0, stream>>>(part_m, part_s, out);
}

// Round 7
// 182.639 us; speedup vs baseline: 1.0396x; 1.0151x over previous
//
#include <hip/hip_runtime.h>
#include <math.h>

#define H 256
#define L 50
#define V 50257
#define LOGIT_BLKS 786   // 786 blk * 4 waves * 16 rows = 50304 >= V
#define H2_BLKS 64

__device__ __forceinline__ float dot4(float4 a, float4 b) {
    return a.x * b.x + a.y * b.y + a.z * b.z + a.w * b.w;
}

__device__ __forceinline__ float wave_reduce_sum(float v) {
#pragma unroll
    for (int m = 32; m >= 1; m >>= 1) v += __shfl_xor(v, m, 64);
    return v;
}

__device__ __forceinline__ float wave_reduce_max(float v) {
#pragma unroll
    for (int m = 32; m >= 1; m >>= 1) v = fmaxf(v, __shfl_xor(v, m, 64));
    return v;
}

__device__ __forceinline__ float sigmoidf(float x) { return 1.0f / (1.0f + __expf(-x)); }

__device__ __forceinline__ void ms_push(float& m, float& s, float x) {
    float mn = fmaxf(m, x);
    s = s * __expf(m - mn) + __expf(x - mn);
    m = mn;
}
__device__ __forceinline__ void ms_merge(float& m, float& s, float om, float os) {
    float M = fmaxf(m, om);
    float a = (m == -INFINITY) ? 0.f : s * __expf(m - M);
    float c = (om == -INFINITY) ? 0.f : os * __expf(om - M);
    m = M; s = a + c;
}

// One GRU output element j computed by one wave.
__device__ __forceinline__ void gru_wave(
    int j, int lane, float4 xv, float4 hv, float hj,
    const float* __restrict__ w_ih, const float* __restrict__ w_hh,
    const float* __restrict__ b_ih, const float* __restrict__ b_hh,
    float* __restrict__ outp)
{
    float gi[3], gh[3];
#pragma unroll
    for (int k = 0; k < 3; ++k) {
        int row = k * H + j;
        const float4* wi4 = (const float4*)(w_ih + (size_t)row * H);
        const float4* wh4 = (const float4*)(w_hh + (size_t)row * H);
        gi[k] = wave_reduce_sum(dot4(wi4[lane], xv)) + b_ih[row];
        gh[k] = wave_reduce_sum(dot4(wh4[lane], hv)) + b_hh[row];
    }
    if (lane == 0) {
        float r = sigmoidf(gi[0] + gh[0]);
        float z = sigmoidf(gi[1] + gh[1]);
        float n = tanhf(gi[2] + r * gh[2]);
        outp[j] = (1.f - z) * n + z * hj;
    }
}

// ---- K1 (64 blocks): scores (redundant per block, L2-hot) + softmax +
// applied + one comb row per wave. ------------------------------------------
__global__ __launch_bounds__(256) void k_comb(
    const int* __restrict__ token, const float* __restrict__ hidden,
    const float* __restrict__ emb, const float* __restrict__ enc,
    const float* __restrict__ attn_W, const float* __restrict__ attn_b,
    const float* __restrict__ comb_W, const float* __restrict__ comb_b,
    float* __restrict__ ws_x, float* __restrict__ out_aw)
{
    __shared__ __align__(16) float s_eh[2 * H];   // [e|h0] -> [e|applied]
    __shared__ float s_scores[L];
    __shared__ float s_aw[64];
    int b = blockIdx.x, t = threadIdx.x, wid = t >> 6, lane = t & 63;
    int tok = token[0];
    s_eh[t] = emb[(size_t)tok * H + t];
    s_eh[H + t] = hidden[t];
    __syncthreads();
    for (int l = wid; l < L; l += 4) {            // all 50 scores, this block
        float acc = 0.f;
#pragma unroll
        for (int c = 0; c < 8; ++c)
            acc += attn_W[l * 2 * H + c * 64 + lane] * s_eh[c * 64 + lane];
        acc = wave_reduce_sum(acc);
        if (lane == 0) s_scores[l] = fmaxf(acc + attn_b[l], 0.f);  // relu
    }
    __syncthreads();
    if (t < 64) {                                  // softmax over 50, wave 0
        float v = (t < L) ? s_scores[t] : -INFINITY;
        float mx = wave_reduce_max(v);
        float e = (t < L) ? __expf(v - mx) : 0.f;
        float ssum = wave_reduce_sum(e);
        if (t < L) {
            float aw = e / ssum;
            s_aw[t] = aw;
            if (b == 0) out_aw[t] = aw;            // third output
        }
    }
    __syncthreads();
    float app = 0.f;
    for (int l = 0; l < L; ++l) app += s_aw[l] * enc[l * H + t];
    s_eh[H + t] = app;                             // cat = [e|applied]
    __syncthreads();
    int row = b * 4 + wid;
    const float4* c4 = (const float4*)s_eh;
    const float4* W4 = (const float4*)(comb_W + (size_t)row * 2 * H);
    float acc = dot4(W4[lane], c4[lane]) + dot4(W4[lane + 64], c4[lane + 64]);
    acc = wave_reduce_sum(acc);
    if (lane == 0) ws_x[row] = fmaxf(acc + comb_b[row], 0.f);
}

// ---- K2 (128 blocks): bidirectional GRU (hf, hb), wave per (dir, j) --------
__global__ __launch_bounds__(256) void k_gru_fb(
    const float* __restrict__ ws_x, const float* __restrict__ hidden,
    const float* __restrict__ w_ih_f, const float* __restrict__ w_hh_f,
    const float* __restrict__ b_ih_f, const float* __restrict__ b_hh_f,
    const float* __restrict__ w_ih_b, const float* __restrict__ w_hh_b,
    const float* __restrict__ b_ih_b, const float* __restrict__ b_hh_b,
    float* __restrict__ ws_hf, float* __restrict__ ws_hb)
{
    int t = threadIdx.x, wid = t >> 6, lane = t & 63;
    int g = blockIdx.x * 4 + wid;
    int dir = g >> 8, j = g & 255;
    gru_wave(j, lane, ((const float4*)ws_x)[lane], ((const float4*)hidden)[lane],
             hidden[j],
             dir ? w_ih_b : w_ih_f, dir ? w_hh_b : w_hh_f,
             dir ? b_ih_b : b_ih_f, dir ? b_hh_b : b_hh_f,
             dir ? ws_hb : ws_hf);
}

// ---- K3 (64 blocks): h1 = gru(hf, mean(hf,hb)) -----------------------------
__global__ __launch_bounds__(256) void k_gru1(
    const float* __restrict__ ws_hf, const float* __restrict__ ws_hb,
    const float* __restrict__ w_ih_g, const float* __restrict__ w_hh_g,
    const float* __restrict__ b_ih_g, const float* __restrict__ b_hh_g,
    float* __restrict__ ws_h1)
{
    int t = threadIdx.x, wid = t >> 6, lane = t & 63;
    int j = blockIdx.x * 4 + wid;
    float4 av = ((const float4*)ws_hf)[lane];
    float4 bv = ((const float4*)ws_hb)[lane];
    float4 hv = make_float4(0.5f * (av.x + bv.x), 0.5f * (av.y + bv.y),
                            0.5f * (av.z + bv.z), 0.5f * (av.w + bv.w));
    float hj = 0.5f * (ws_hf[j] + ws_hb[j]);
    gru_wave(j, lane, av, hv, hj, w_ih_g, w_hh_g, b_ih_g, b_hh_g, ws_h1);
}

// ---- K4: logits + per-block (m,s) partials (0..785) || h2 (786..849) -------
// R4's measured-good inner loop: 16 rows per wave, 2 rows in flight.
__global__ __launch_bounds__(256) void k_logits(
    const float* __restrict__ out_W, const float* __restrict__ out_b,
    const float* __restrict__ h1, const float* __restrict__ ws_hb,
    const float* __restrict__ w_ih_g, const float* __restrict__ w_hh_g,
    const float* __restrict__ b_ih_g, const float* __restrict__ b_hh_g,
    float* __restrict__ logits, float* __restrict__ out_h2,
    float* __restrict__ part_m, float* __restrict__ part_s)
{
    int b = blockIdx.x, t = threadIdx.x, wid = t >> 6, lane = t & 63;
    if (b >= LOGIT_BLKS) {
        int j = (b - LOGIT_BLKS) * 4 + wid;    // h2 = gru(hb, h1)
        gru_wave(j, lane, ((const float4*)ws_hb)[lane], ((const float4*)h1)[lane],
                 h1[j], w_ih_g, w_hh_g, b_ih_g, b_hh_g, out_h2);
        return;
    }
    __shared__ float s_m4[4], s_s4[4];
    float4 hv = ((const float4*)h1)[lane];
    int base = (b * 4 + wid) * 16;
    float m = -INFINITY, s = 0.f;
#pragma unroll 1
    for (int k = 0; k < 16; k += 2) {
        int v = base + k;
        if (v >= V) break;
        const float4* W0 = (const float4*)(out_W + (size_t)v * H);
        float4 a0 = W0[lane];
        bool has2 = (v + 1 < V);
        float4 a1 = has2 ? ((const float4*)(out_W + (size_t)(v + 1) * H))[lane]
                         : make_float4(0.f, 0.f, 0.f, 0.f);
        float x0 = wave_reduce_sum(dot4(a0, hv)) + out_b[v];
        float x1 = wave_reduce_sum(dot4(a1, hv));
        if (lane == 0) logits[v] = x0;
        ms_push(m, s, x0);
        if (has2) {
            x1 += out_b[v + 1];
            if (lane == 0) logits[v + 1] = x1;
            ms_push(m, s, x1);
        }
    }
    if (lane == 0) { s_m4[wid] = m; s_s4[wid] = s; }
    __syncthreads();
    if (t == 0) {
        float M = s_m4[0], S = s_s4[0];
#pragma unroll
        for (int q = 1; q < 4; ++q) ms_merge(M, S, s_m4[q], s_s4[q]);
        part_m[b] = M; part_s[b] = S;
    }
}

// ---- K5 (197 blocks): fold 786 partials -> lse (replicated); subtract ------
__global__ __launch_bounds__(256) void k_final(
    const float* __restrict__ part_m, const float* __restrict__ part_s,
    float* __restrict__ logits)
{
    __shared__ float s_m4[4], s_s4[4];
    __shared__ float s_bcast;
    int t = threadIdx.x, wid = t >> 6, lane = t & 63;
    float m = -INFINITY, s = 0.f;
    for (int idx = t; idx < LOGIT_BLKS; idx += 256)
        ms_merge(m, s, part_m[idx], part_s[idx]);
#pragma unroll
    for (int d = 32; d >= 1; d >>= 1) {
        float om = __shfl_xor(m, d, 64);
        float os = __shfl_xor(s, d, 64);
        ms_merge(m, s, om, os);
    }
    if (lane == 0) { s_m4[wid] = m; s_s4[wid] = s; }
    __syncthreads();
    if (t == 0) {
        float M = s_m4[0], S = s_s4[0];
#pragma unroll
        for (int q = 1; q < 4; ++q) ms_merge(M, S, s_m4[q], s_s4[q]);
        s_bcast = M + logf(S);
    }
    __syncthreads();
    float lse = s_bcast;
    int i = blockIdx.x * 256 + t;
    if (i < V) logits[i] -= lse;
}

extern "C" void kernel_launch(void* const* d_in, const int* in_sizes, int n_in,
                              void* d_out, int out_size, void* d_ws, size_t ws_size,
                              hipStream_t stream)
{
    const int*   token  = (const int*)d_in[0];
    const float* hidden = (const float*)d_in[1];
    const float* enc    = (const float*)d_in[2];
    const float* emb    = (const float*)d_in[3];
    const float* attn_W = (const float*)d_in[4];
    const float* attn_b = (const float*)d_in[5];
    const float* comb_W = (const float*)d_in[6];
    const float* comb_b = (const float*)d_in[7];
    const float* w_ih_f = (const float*)d_in[8];
    const float* w_hh_f = (const float*)d_in[9];
    const float* b_ih_f = (const float*)d_in[10];
    const float* b_hh_f = (const float*)d_in[11];
    const float* w_ih_b = (const float*)d_in[12];
    const float* w_hh_b = (const float*)d_in[13];
    const float* b_ih_b = (const float*)d_in[14];
    const float* b_hh_b = (const float*)d_in[15];
    const float* w_ih_g = (const float*)d_in[16];
    const float* w_hh_g = (const float*)d_in[17];
    const float* b_ih_g = (const float*)d_in[18];
    const float* b_hh_g = (const float*)d_in[19];
    const float* out_W  = (const float*)d_in[20];
    const float* out_b  = (const float*)d_in[21];

    float* out = (float*)d_out;   // [V logp | H h2 | L aw]
    float* ws  = (float*)d_ws;
    float* ws_x   = ws;               // 256
    float* ws_hf  = ws + 256;         // 256
    float* ws_hb  = ws + 512;         // 256
    float* ws_h1  = ws + 768;         // 256
    float* part_m = ws + 1088;        // 786
    float* part_s = ws + 1888;        // 786

    k_comb<<<64, 256, 0, stream>>>(token, hidden, emb, enc, attn_W, attn_b,
                                   comb_W, comb_b, ws_x, out + V + H);
    k_gru_fb<<<128, 256, 0, stream>>>(ws_x, hidden,
                                      w_ih_f, w_hh_f, b_ih_f, b_hh_f,
                                      w_ih_b, w_hh_b, b_ih_b, b_hh_b,
                                      ws_hf, ws_hb);
    k_gru1<<<64, 256, 0, stream>>>(ws_hf, ws_hb,
                                   w_ih_g, w_hh_g, b_ih_g, b_hh_g, ws_h1);
    k_logits<<<LOGIT_BLKS + H2_BLKS, 256, 0, stream>>>(
        out_W, out_b, ws_h1, ws_hb, w_ih_g, w_hh_g, b_ih_g, b_hh_g,
        out, out + V, part_m, part_s);
    k_final<<<197, 256, 0, stream>>>(part_m, part_s, out);
}